// Round 5
// baseline (22.093 us; speedup 1.0000x reference)
//
#include <hip/hip_runtime.h>
#include <hip/hip_bf16.h>

// Decoder step, MI355X. Live math only:
//   pred = 0 exactly (log_softmax over size-1 axis)
//   h,c  = single LSTM cell step
// ONE dispatch:
//   blocks 0..99    : GEMM (gates = [x|h] @ [w_ih|w_hh]^T) with LDS-staged
//                     fp32->bf16 conversion, + in-register LSTM epilogue
//   blocks 100..2047: grid-stride zero of the 32.77MB pred region (concurrent)

#define HH 400          // hidden
#define BB 256          // batch
#define KK 800          // concat K = [x | h_prev]
#define PRED_N 8192000  // 256*32000
#define BH_N   102400   // 256*400

#define GEMM_BLOCKS 100
#define TOTAL_BLOCKS 2048
#define ZERO_BLOCKS (TOTAL_BLOCKS - GEMM_BLOCKS)
#define ZERO_THREADS (ZERO_BLOCKS * 256)
#define PRED_VEC (PRED_N / 4)     // 2048000 f32x4 stores

#define BK 160                    // k-tile (800 = 5 * 160); 160-chunks never straddle k=400
#define NSTEP 5
#define LDS_STRIDE 168            // 160 + 8 bf16 pad -> 336B row stride -> <=2-way bank conflict

typedef __attribute__((ext_vector_type(8))) short short8;
typedef __attribute__((ext_vector_type(4))) float f32x4;

__device__ __forceinline__ float sigmoidf_(float x) {
    return 1.0f / (1.0f + __expf(-x));
}
__device__ __forceinline__ float tanh_stable(float x) {
    float ax = fabsf(x);
    float e  = __expf(-2.0f * ax);
    float r  = (1.0f - e) / (1.0f + e);
    return copysignf(r, x);
}

// 8 contiguous fp32 (16B-aligned) -> bf16x8
__device__ __forceinline__ short8 cvt8(const float* __restrict__ s) {
    f32x4 v0 = *reinterpret_cast<const f32x4*>(s);
    f32x4 v1 = *reinterpret_cast<const f32x4*>(s + 4);
    union { short8 sv; __hip_bfloat16 h[8]; } u;
#pragma unroll
    for (int i = 0; i < 4; ++i) {
        u.h[i]     = __float2bfloat16(v0[i]);
        u.h[i + 4] = __float2bfloat16(v1[i]);
    }
    return u.sv;
}

__launch_bounds__(256)
__global__ void decoder_one_kernel(const int* __restrict__ prev,
                                   const float* __restrict__ h0,
                                   const float* __restrict__ c0,
                                   const float* __restrict__ emb,
                                   const float* __restrict__ wih,
                                   const float* __restrict__ whh,
                                   const float* __restrict__ bih,
                                   const float* __restrict__ bhh,
                                   float* __restrict__ out) {
    __shared__ short wlds[64 * LDS_STRIDE];   // 64 gate rows (4 gates x 16 cols) x BK
    __shared__ short xlds[64 * LDS_STRIDE];   // 64 batch rows x BK

    if (blockIdx.x >= GEMM_BLOCKS) {
        // ---- zero the pred region (exactly 0: log_softmax over size-1 axis) ----
        const int tid = (blockIdx.x - GEMM_BLOCKS) * 256 + threadIdx.x;
        f32x4 z = {0.f, 0.f, 0.f, 0.f};
        f32x4* p = reinterpret_cast<f32x4*>(out);
        for (int i = tid; i < PRED_VEC; i += ZERO_THREADS) p[i] = z;
        return;
    }

    const int jt = blockIdx.x >> 2;   // 0..24
    const int bt = blockIdx.x & 3;    // 0..3
    const int j0 = jt * 16;
    const int b0 = bt * 64;

    const int wave = threadIdx.x >> 6;
    const int lane = threadIdx.x & 63;

    // ---- staging coords: thread t loads 40 fp32 of row (t>>2) at col (t&3)*40 ----
    const int sr = threadIdx.x >> 2;        // lds row 0..63
    const int kb = (threadIdx.x & 3) * 40;  // col base within k-tile

    // W lds row sr -> gate (sr>>4), col j0+(sr&15): global row n = gate*400 + j
    const int wn = (sr >> 4) * HH + j0 + (sr & 15);
    const float* wrow_lo = wih + (size_t)wn * HH;   // k < 400
    const float* wrow_hi = whh + (size_t)wn * HH;   // k >= 400
    // X lds row sr -> batch b0+sr
    const int xb = b0 + sr;
    const float* xrow_lo = emb + (size_t)prev[xb] * HH;
    const float* xrow_hi = h0  + (size_t)xb * HH;

    // ---- MFMA fragment coords ----
    const int fr = lane & 15;          // A: batch row within wave tile; B: gate col
    const int fk = (lane >> 4) * 8;    // k sub-offset within K=32 step

    f32x4 ai = {0.f, 0.f, 0.f, 0.f};
    f32x4 af = {0.f, 0.f, 0.f, 0.f};
    f32x4 ag = {0.f, 0.f, 0.f, 0.f};
    f32x4 ao = {0.f, 0.f, 0.f, 0.f};

    for (int step = 0; step < NSTEP; ++step) {
        const int ka = step * BK + kb;           // absolute k of this thread's 40-chunk
        const bool lo = ka < HH;                 // 40-chunks never straddle k=400
        const int ks = lo ? ka : ka - HH;
        const float* ws = (lo ? wrow_lo : wrow_hi) + ks;
        const float* xs = (lo ? xrow_lo : xrow_hi) + ks;

        if (step) __syncthreads();               // waves done reading previous tile
#pragma unroll
        for (int i = 0; i < 5; ++i) {
            *reinterpret_cast<short8*>(&wlds[sr * LDS_STRIDE + kb + i * 8]) = cvt8(ws + i * 8);
            *reinterpret_cast<short8*>(&xlds[sr * LDS_STRIDE + kb + i * 8]) = cvt8(xs + i * 8);
        }
        __syncthreads();

#pragma unroll
        for (int kk = 0; kk < 5; ++kk) {
            const int kc = kk * 32 + fk;
            short8 a = *reinterpret_cast<const short8*>(&xlds[(wave * 16 + fr) * LDS_STRIDE + kc]);
            ai = __builtin_amdgcn_mfma_f32_16x16x32_bf16(
                a, *reinterpret_cast<const short8*>(&wlds[(0 * 16 + fr) * LDS_STRIDE + kc]), ai, 0, 0, 0);
            af = __builtin_amdgcn_mfma_f32_16x16x32_bf16(
                a, *reinterpret_cast<const short8*>(&wlds[(1 * 16 + fr) * LDS_STRIDE + kc]), af, 0, 0, 0);
            ag = __builtin_amdgcn_mfma_f32_16x16x32_bf16(
                a, *reinterpret_cast<const short8*>(&wlds[(2 * 16 + fr) * LDS_STRIDE + kc]), ag, 0, 0, 0);
            ao = __builtin_amdgcn_mfma_f32_16x16x32_bf16(
                a, *reinterpret_cast<const short8*>(&wlds[(3 * 16 + fr) * LDS_STRIDE + kc]), ao, 0, 0, 0);
        }
    }

    const int j = j0 + fr;
    const float bi = bih[0 * HH + j] + bhh[0 * HH + j];
    const float bf = bih[1 * HH + j] + bhh[1 * HH + j];
    const float bg = bih[2 * HH + j] + bhh[2 * HH + j];
    const float bo = bih[3 * HH + j] + bhh[3 * HH + j];

#pragma unroll
    for (int r = 0; r < 4; ++r) {
        const int b = b0 + wave * 16 + (lane >> 4) * 4 + r;   // C/D row mapping (m89-verified)
        float vi = ai[r] + bi;
        float vf = af[r] + bf;
        float vg = ag[r] + bg;
        float vo = ao[r] + bo;
        float ig = sigmoidf_(vi);
        float fg = sigmoidf_(vf);
        float gg = tanh_stable(vg);
        float og = sigmoidf_(vo);
        float cp = c0[(size_t)b * HH + j];
        float c  = fg * cp + ig * gg;
        float h  = og * tanh_stable(c);
        out[PRED_N + (size_t)b * HH + j]        = h;
        out[PRED_N + BH_N + (size_t)b * HH + j] = c;
    }
}

extern "C" void kernel_launch(void* const* d_in, const int* in_sizes, int n_in,
                              void* d_out, int out_size, void* d_ws, size_t ws_size,
                              hipStream_t stream) {
    const int*   prev = (const int*)d_in[0];
    const float* h0   = (const float*)d_in[1];
    const float* c0   = (const float*)d_in[2];
    // d_in[3] encoder_outputs: dead (feeds only pred, which log_softmax(axis=1,size1) zeroes)
    const float* emb  = (const float*)d_in[4];
    const float* wih  = (const float*)d_in[5];
    const float* whh  = (const float*)d_in[6];
    const float* bih  = (const float*)d_in[7];
    const float* bhh  = (const float*)d_in[8];
    // d_in[9..14]: W1/W2/W_w/W_b dead for the same reason.

    float* out = (float*)d_out;

    decoder_one_kernel<<<TOTAL_BLOCKS, 256, 0, stream>>>(
        prev, h0, c0, emb, wih, whh, bih, bhh, out);
}

// Round 6
// 21.420 us; speedup vs baseline: 1.0314x; 1.0314x over previous
//
#include <hip/hip_runtime.h>
#include <hip/hip_bf16.h>

// Decoder step, MI355X. Live math only:
//   pred = 0 exactly (log_softmax over size-1 axis)
//   h,c  = single LSTM cell step
// Two dispatches:
//   k1: pack [x|h] and [w_ih|w_hh] to bf16 (coalesced, NT weight loads)
//   k2: ids 0..127 = XCD-swizzled MFMA GEMM + LSTM epilogue (4 bt of a jt
//       share an XCD -> wcat slice fetched once per XCD);
//       ids 128..2047 = NT-store zero of the 32.77MB pred region (concurrent)

#define HH 400          // hidden
#define BB 256          // batch
#define KK 800          // concat K = [x | h_prev]
#define NG 1600         // 4*H gate rows
#define PRED_N 8192000  // 256*32000
#define BH_N   102400   // 256*400

#define W_CHUNKS (NG * KK / 8)                  // 160000 short8 chunks
#define X_CHUNKS (BB * KK / 8)                  // 25600
#define PACK_THREADS (W_CHUNKS + X_CHUNKS)      // 185600
#define PACK_BLOCKS ((PACK_THREADS + 255) / 256)

#define GEMM_SLOTS 128                          // 25 jt x 4 bt live + 28 idle
#define K2_BLOCKS 2048
#define ZERO_BLOCKS (K2_BLOCKS - GEMM_SLOTS)    // 1920
#define ZERO_THREADS (ZERO_BLOCKS * 256)        // 491520
#define PRED_VEC (PRED_N / 4)                   // 2048000 f32x4 stores

typedef __attribute__((ext_vector_type(8))) short short8;
typedef __attribute__((ext_vector_type(4))) float f32x4;

__device__ __forceinline__ float sigmoidf_(float x) {
    return 1.0f / (1.0f + __expf(-x));
}
__device__ __forceinline__ float tanh_stable(float x) {
    float ax = fabsf(x);
    float e  = __expf(-2.0f * ax);
    float r  = (1.0f - e) / (1.0f + e);
    return copysignf(r, x);
}

// 8 contiguous fp32 (16B-aligned) -> bf16x8, nontemporal (read-once stream)
__device__ __forceinline__ short8 cvt8_nt(const float* __restrict__ s) {
    f32x4 v0 = __builtin_nontemporal_load(reinterpret_cast<const f32x4*>(s));
    f32x4 v1 = __builtin_nontemporal_load(reinterpret_cast<const f32x4*>(s) + 1);
    union { short8 sv; __hip_bfloat16 h[8]; } u;
#pragma unroll
    for (int i = 0; i < 4; ++i) {
        u.h[i]     = __float2bfloat16(v0[i]);
        u.h[i + 4] = __float2bfloat16(v1[i]);
    }
    return u.sv;
}

// k1: pack weights + x to bf16. All accesses flat-contiguous/coalesced.
__launch_bounds__(256)
__global__ void pack_kernel(const int* __restrict__ prev,
                            const float* __restrict__ h0,
                            const float* __restrict__ emb,
                            const float* __restrict__ wih,
                            const float* __restrict__ whh,
                            __hip_bfloat16* __restrict__ xcat,
                            __hip_bfloat16* __restrict__ wcat) {
    const int tid = blockIdx.x * 256 + threadIdx.x;

    if (tid < W_CHUNKS) {
        // Wcat[n][k] = k<400 ? wih[n][k] : whh[n][k-400]; chunks don't straddle (400%8==0)
        const int e0 = tid * 8;
        const int n  = e0 / KK;
        const int k  = e0 % KK;
        const float* src = (k < HH) ? (wih + (size_t)n * HH + k)
                                    : (whh + (size_t)n * HH + (k - HH));
        reinterpret_cast<short8*>(wcat)[tid] = cvt8_nt(src);
    } else if (tid < PACK_THREADS) {
        const int t  = tid - W_CHUNKS;
        const int e0 = t * 8;
        const int b  = e0 / KK;
        const int k  = e0 % KK;
        const float* src = (k < HH) ? (emb + (size_t)prev[b] * HH + k)
                                    : (h0 + (size_t)b * HH + (k - HH));
        reinterpret_cast<short8*>(xcat)[t] = cvt8_nt(src);
    }
}

// k2: ids 0..127 GEMM (gates = Xcat @ Wcat^T + biases) + LSTM epilogue;
//     ids 128..   grid-stride NT-zero of the 32.77MB pred region (overlaps GEMM).
__launch_bounds__(256)
__global__ void lstm_zero_kernel(const __hip_bfloat16* __restrict__ xcat,
                                 const __hip_bfloat16* __restrict__ wcat,
                                 const float* __restrict__ bih,
                                 const float* __restrict__ bhh,
                                 const float* __restrict__ c0,
                                 float* __restrict__ out) {
    if (blockIdx.x >= GEMM_SLOTS) {
        const int tid = (blockIdx.x - GEMM_SLOTS) * 256 + threadIdx.x;
        f32x4 z = {0.f, 0.f, 0.f, 0.f};
        f32x4* p = reinterpret_cast<f32x4*>(out);
        for (int i = tid; i < PRED_VEC; i += ZERO_THREADS)
            __builtin_nontemporal_store(z, p + i);
        return;
    }

    // XCD-aware decode: ids of the 4 bt-blocks of one jt differ by 8
    // (id = (jt&7) + 32*(jt>>3) + 8*bt), so id%8 — the XCD — is fixed per jt.
    const int r  = blockIdx.x & 7;
    const int q  = blockIdx.x >> 3;
    const int jt = r + 8 * (q >> 2);      // 0..31 (25..31 idle)
    const int bt = q & 3;
    if (jt >= 25) return;

    const int wave = threadIdx.x >> 6;
    const int lane = threadIdx.x & 63;

    const int b0   = bt * 64 + wave * 16;
    const int j    = jt * 16 + (lane & 15);   // gate column
    const int arow = b0 + (lane & 15);        // A row (batch)
    const int koff = (lane >> 4) * 8;         // k sub-offset within K=32 step

    const short8* ap  = reinterpret_cast<const short8*>(xcat + (size_t)arow * KK + koff);
    const short8* bp0 = reinterpret_cast<const short8*>(wcat + (size_t)(0 * HH + j) * KK + koff);
    const short8* bp1 = reinterpret_cast<const short8*>(wcat + (size_t)(1 * HH + j) * KK + koff);
    const short8* bp2 = reinterpret_cast<const short8*>(wcat + (size_t)(2 * HH + j) * KK + koff);
    const short8* bp3 = reinterpret_cast<const short8*>(wcat + (size_t)(3 * HH + j) * KK + koff);

    f32x4 ai = {0.f, 0.f, 0.f, 0.f};
    f32x4 af = {0.f, 0.f, 0.f, 0.f};
    f32x4 ag = {0.f, 0.f, 0.f, 0.f};
    f32x4 ao = {0.f, 0.f, 0.f, 0.f};

#pragma unroll
    for (int ks = 0; ks < KK / 32; ++ks) {
        short8 a = ap[ks * 4];   // +32 bf16 per step
        ai = __builtin_amdgcn_mfma_f32_16x16x32_bf16(a, bp0[ks * 4], ai, 0, 0, 0);
        af = __builtin_amdgcn_mfma_f32_16x16x32_bf16(a, bp1[ks * 4], af, 0, 0, 0);
        ag = __builtin_amdgcn_mfma_f32_16x16x32_bf16(a, bp2[ks * 4], ag, 0, 0, 0);
        ao = __builtin_amdgcn_mfma_f32_16x16x32_bf16(a, bp3[ks * 4], ao, 0, 0, 0);
    }

    const float bi = bih[0 * HH + j] + bhh[0 * HH + j];
    const float bf = bih[1 * HH + j] + bhh[1 * HH + j];
    const float bg = bih[2 * HH + j] + bhh[2 * HH + j];
    const float bo = bih[3 * HH + j] + bhh[3 * HH + j];

#pragma unroll
    for (int rr = 0; rr < 4; ++rr) {
        const int b = b0 + (lane >> 4) * 4 + rr;   // C/D row mapping (m89-verified)
        float vi = ai[rr] + bi;
        float vf = af[rr] + bf;
        float vg = ag[rr] + bg;
        float vo = ao[rr] + bo;
        float ig = sigmoidf_(vi);
        float fg = sigmoidf_(vf);
        float gg = tanh_stable(vg);
        float og = sigmoidf_(vo);
        float cp = c0[(size_t)b * HH + j];
        float c  = fg * cp + ig * gg;
        float h  = og * tanh_stable(c);
        __builtin_nontemporal_store(h, out + PRED_N + (size_t)b * HH + j);
        __builtin_nontemporal_store(c, out + PRED_N + BH_N + (size_t)b * HH + j);
    }
}

extern "C" void kernel_launch(void* const* d_in, const int* in_sizes, int n_in,
                              void* d_out, int out_size, void* d_ws, size_t ws_size,
                              hipStream_t stream) {
    const int*   prev = (const int*)d_in[0];
    const float* h0   = (const float*)d_in[1];
    const float* c0   = (const float*)d_in[2];
    // d_in[3] encoder_outputs: dead (feeds only pred, which log_softmax(axis=1,size1) zeroes)
    const float* emb  = (const float*)d_in[4];
    const float* wih  = (const float*)d_in[5];
    const float* whh  = (const float*)d_in[6];
    const float* bih  = (const float*)d_in[7];
    const float* bhh  = (const float*)d_in[8];
    // d_in[9..14]: W1/W2/W_w/W_b dead for the same reason.

    float* out = (float*)d_out;

    __hip_bfloat16* xcat = (__hip_bfloat16*)d_ws;                    // 256*800 bf16
    __hip_bfloat16* wcat = (__hip_bfloat16*)((char*)d_ws + 409600);  // 1600*800 bf16

    pack_kernel<<<PACK_BLOCKS, 256, 0, stream>>>(prev, h0, emb, wih, whh, xcat, wcat);

    lstm_zero_kernel<<<K2_BLOCKS, 256, 0, stream>>>(xcat, wcat, bih, bhh, c0, out);
}